// Round 14
// baseline (1399.747 us; speedup 1.0000x reference)
//
#include <hip/hip_runtime.h>

// ODENet: y_{t+1} = y_t + f(x_t, y_t),  f = W3^T tanh(W2^T tanh(x*W1[0] + y*W1[1] + b1) + b2) + b3
// out[t][b] = y_t (pre-update state).  SEQ=2048 sequential steps, BATCH=512 independent chains.
//
// Round-14: ONE barrier per step via T/E-split MFMA. h1 = T + s*E (verified linearization)
// and MFMA is linear in A, so feed T at rows m=0,4 and E at rows m=8,12 (same 16 MFMAs) and
// apply the fold AFTER the MFMA in fp32: h2pre = accT + s*accE. The A-write then doesn't
// depend on the fold -> single __syncthreads per step; fold/y/T-E overlap the MFMA drain.
// Hazards: A_lds and partial double-buffered; every cross-iter WAR/RAW spans one barrier.
// C rows 0/4/8/12 -> lanes 0-15/16-31/32-47/48-63 reg0; E-part via __shfl_xor(acc,32).
// LDA=264: A rows start at banks 0/4/8/12 -> worst 2-way dup on A-reads (free, m136).
// Retained: x in LDS, y staged in LDS + one flush, exp2-tanh, DPP row16 reduce, M=2 chains.

#define SEQ 2048
#define BATCH 512
#define HID 256
#define LDA 264  // padded row stride (ushorts)

typedef __bf16 bf16x8 __attribute__((ext_vector_type(8)));
typedef short short8 __attribute__((ext_vector_type(8)));
typedef float f32x4 __attribute__((ext_vector_type(4)));

__device__ __forceinline__ unsigned short f2bf_rne(float f) {
  unsigned u = __builtin_bit_cast(unsigned, f);
  u += 0x7fffu + ((u >> 16) & 1u);
  return (unsigned short)(u >> 16);
}

// Exact tanh via exp2: tanh(x) = 1 - 2/(exp2(2*log2e*x) + 1). No clamp needed.
__device__ __forceinline__ float tanh_e(float x) {
  float t = __builtin_amdgcn_exp2f(x * 2.8853900817779268f);
  return __builtin_fmaf(-2.f, __builtin_amdgcn_rcpf(t + 1.f), 1.f);
}

// Sum over each 16-lane DPP row; valid in lane 15 of the row.
__device__ __forceinline__ float row16_sum_to_lane15(float v) {
  int s;
  s = __builtin_amdgcn_update_dpp(0, __builtin_bit_cast(int, v), 0x111, 0xf, 0xf, true);
  v += __builtin_bit_cast(float, s);
  s = __builtin_amdgcn_update_dpp(0, __builtin_bit_cast(int, v), 0x112, 0xf, 0xf, true);
  v += __builtin_bit_cast(float, s);
  s = __builtin_amdgcn_update_dpp(0, __builtin_bit_cast(int, v), 0x114, 0xf, 0xf, true);
  v += __builtin_bit_cast(float, s);
  s = __builtin_amdgcn_update_dpp(0, __builtin_bit_cast(int, v), 0x118, 0xf, 0xf, true);
  v += __builtin_bit_cast(float, s);
  return v;
}

// Pack W2 (256x256 fp32, row-major [k][c]) into bf16 B-fragments.
// ws[(((tile*8)+kc)*64 + lane)*8 + e] = bf16(W2[k][c]) with
//   k = kc*32 + (lane>>4)*8 + e,  c = tile*16 + (lane&15)
__global__ void pack_w2_kernel(const float* __restrict__ W2,
                               unsigned short* __restrict__ ws) {
  int idx = blockIdx.x * 256 + threadIdx.x;     // 0..65535
  int e    = idx & 7;
  int l    = (idx >> 3) & 63;
  int kc   = (idx >> 9) & 7;
  int tile = idx >> 12;                         // 0..15
  int k = kc * 32 + (l >> 4) * 8 + e;
  int c = tile * 16 + (l & 15);
  ws[idx] = f2bf_rne(W2[k * HID + c]);
}

__global__ __launch_bounds__(512, 1) void odenet_kernel(
    const float* __restrict__ x, const float* __restrict__ W1,
    const float* __restrict__ b1, const unsigned short* __restrict__ wsW2,
    const float* __restrict__ b2, const float* __restrict__ W3,
    const float* __restrict__ b3, const float* __restrict__ state0,
    float* __restrict__ out) {
  __shared__ __align__(16) unsigned short A_lds[2][4 * LDA]; // [buf][row T0,T1,E0,E1]
  __shared__ __align__(16) float partial[2][2][8];           // [buf][chain][wave]
  __shared__ __align__(16) float2 x_lds[SEQ];                // 16 KB
  __shared__ __align__(16) float2 y_lds[SEQ];                // 16 KB

  const int tid  = threadIdx.x;   // 0..511
  const int lane = tid & 63;
  const int wave = tid >> 6;      // 0..7
  const int rh   = tid >> 8;      // own chain
  const int j    = tid & 255;     // own h1 column
  const int b0   = blockIdx.x * 2;

  // --- persistent constants ---
  const float w10 = W1[j];
  const float w11 = W1[HID + j];
  const float b1j = b1[j];
  const float b3v = b3[0];
  const int c0 = wave * 32 + (lane & 15);
  const int c1 = c0 + 16;
  const float b2c0 = b2[c0], w3c0 = W3[c0];
  const float b2c1 = b2[c1], w3c1 = W3[c1];

  // --- B fragments: wave owns tiles {2w, 2w+1} ---
  short8 bf0[8], bf1[8];
  {
    const short8* wp = (const short8*)wsW2;
    const int t0 = wave * 2;
#pragma unroll
    for (int kc = 0; kc < 8; ++kc) {
      bf0[kc] = wp[((t0    ) * 8 + kc) * 64 + lane];
      bf1[kc] = wp[((t0 + 1) * 8 + kc) * 64 + lane];
    }
  }

  // --- preload x into LDS (one-time) ---
  {
    const float* xg = x + b0;
#pragma unroll
    for (int k = 0; k < 4; ++k) {
      const int t = tid + k * 512;
      x_lds[t] = *(const float2*)&xg[t * BATCH];
    }
  }

  // --- A-read: storage row g=(lane>>2)&3 (T0,T1,E0,E1 -> MFMA rows m=0,4,8,12 at
  //     lanes with lane&15 == 0,4,8,12; other lanes read duplicates = broadcast) ---
  const int aoff = ((lane >> 2) & 3) * LDA + (lane >> 4) * 8; // ushort index

  const f32x4 kZero = {0.f, 0.f, 0.f, 0.f};

  const float2 y_init = *(const float2*)&state0[b0];
  float y_own = rh ? y_init.y : y_init.x;

  // --- partials[1] init: fold at t=0 reads buf 1; 8 entries of -b3/8 -> s = -b3, f = 0 ---
  if (tid < 16) partial[1][tid >> 3][tid & 7] = -0.125f * b3v;

  // --- T/E for step 0: linearization point xa(0) + w11*(y_init + b3) ---
  float T, E;
  {
    // x_lds not yet synced; read x directly from global for step 0 (outside loop)
    const float2 x0 = *(const float2*)&x[b0];
    const float xv = rh ? x0.y : x0.x;
    const float xa0 = __builtin_fmaf(xv, w10, b1j);
    T = tanh_e(__builtin_fmaf(b3v, w11, __builtin_fmaf(y_own, w11, xa0)));
    E = w11 * __builtin_fmaf(-T, T, 1.f);
  }
  __syncthreads(); // x_lds + partial[1] visible (acts as the barrier preceding step 0)

  for (int t = 0; t < SEQ; ++t) {
    const int buf = t & 1;
    // --- write T,E rows (bf16) into A buffer for this step ---
    A_lds[buf][rh * LDA + j]       = f2bf_rne(T);
    A_lds[buf][(2 + rh) * LDA + j] = f2bf_rne(E);
    __syncthreads(); // THE barrier: h1 rows visible; prev partials visible

    // --- A-fragments ---
    const unsigned short* ab = &A_lds[buf][0];
    short8 areg[8];
#pragma unroll
    for (int kc = 0; kc < 8; ++kc)
      areg[kc] = *(const short8*)&ab[aoff + kc * 32];

    // --- 2 tiles x K=256: accT in lanes 0-31 reg0, accE in lanes 32-63 reg0 ---
    f32x4 acc0, acc1;
    {
      const bf16x8 a = __builtin_bit_cast(bf16x8, areg[0]);
      acc0 = __builtin_amdgcn_mfma_f32_16x16x32_bf16(a, __builtin_bit_cast(bf16x8, bf0[0]), kZero, 0, 0, 0);
      acc1 = __builtin_amdgcn_mfma_f32_16x16x32_bf16(a, __builtin_bit_cast(bf16x8, bf1[0]), kZero, 0, 0, 0);
    }
#pragma unroll
    for (int kc = 1; kc < 8; ++kc) {
      const bf16x8 a = __builtin_bit_cast(bf16x8, areg[kc]);
      acc0 = __builtin_amdgcn_mfma_f32_16x16x32_bf16(a, __builtin_bit_cast(bf16x8, bf0[kc]), acc0, 0, 0, 0);
      acc1 = __builtin_amdgcn_mfma_f32_16x16x32_bf16(a, __builtin_bit_cast(bf16x8, bf1[kc]), acc1, 0, 0, 0);
    }

    // --- fold prev step's partials (overlaps MFMA drain; independent of acc) ---
    const f32x4 q0a = *(const f32x4*)&partial[buf ^ 1][0][0];
    const f32x4 q0b = *(const f32x4*)&partial[buf ^ 1][0][4];
    const f32x4 q1a = *(const f32x4*)&partial[buf ^ 1][1][0];
    const f32x4 q1b = *(const f32x4*)&partial[buf ^ 1][1][4];
    const float s0sum = ((q0a[0] + q0a[1]) + (q0a[2] + q0a[3])) +
                        ((q0b[0] + q0b[1]) + (q0b[2] + q0b[3])); // = f(t-1) - b3
    const float s1sum = ((q1a[0] + q1a[1]) + (q1a[2] + q1a[3])) +
                        ((q1b[0] + q1b[1]) + (q1b[2] + q1b[3]));

    // --- y update -> Y_t, stage, next T/E (all in the MFMA shadow) ---
    const float s_own = rh ? s1sum : s0sum;
    y_own += s_own + b3v; // DT = 1.0; y_own = state entering step t
    if (j == 0) ((float*)&y_lds[t])[rh] = y_own;
    {
      const float2 xr = x_lds[(t + 1 < SEQ) ? t + 1 : t];
      const float xv = rh ? xr.y : xr.x;
      const float xaN = __builtin_fmaf(xv, w10, b1j);
      T = tanh_e(__builtin_fmaf(b3v, w11, __builtin_fmaf(y_own, w11, xaN)));
      E = w11 * __builtin_fmaf(-T, T, 1.f);
    }

    // --- tail: h2pre = accT + s*accE (E-part via cross-half shfl), tanh, dot W3 ---
    const float s_lane = ((lane >> 4) & 1) ? s1sum : s0sum;
    const float e0 = __shfl_xor(acc0[0], 32, 64);
    const float e1 = __shfl_xor(acc1[0], 32, 64);
    const float h0 = __builtin_fmaf(s_lane, e0, acc0[0]); // lanes 0-31 valid
    const float h1v = __builtin_fmaf(s_lane, e1, acc1[0]);
    const float sres = tanh_e(h0 + b2c0) * w3c0 +
                       tanh_e(h1v + b2c1) * w3c1;
    const float r = row16_sum_to_lane15(sres);
    if ((lane & 15) == 15 && lane < 32)
      partial[buf][lane >> 4][wave] = r; // read at t+1 after its barrier
    // no second barrier: all cross-iteration hazards span the next iteration's barrier
  }

  // --- flush y staging to global (one-time) ---
#pragma unroll
  for (int k = 0; k < 4; ++k) {
    const int t = tid + k * 512;
    *(float2*)&out[t * BATCH + b0] = y_lds[t];
  }
}

extern "C" void kernel_launch(void* const* d_in, const int* in_sizes, int n_in,
                              void* d_out, int out_size, void* d_ws, size_t ws_size,
                              hipStream_t stream) {
  const float* x  = (const float*)d_in[0];
  const float* W1 = (const float*)d_in[1];
  const float* b1 = (const float*)d_in[2];
  const float* W2 = (const float*)d_in[3];
  const float* b2 = (const float*)d_in[4];
  const float* W3 = (const float*)d_in[5];
  const float* b3 = (const float*)d_in[6];
  const float* s0 = (const float*)d_in[7];
  unsigned short* ws = (unsigned short*)d_ws; // 65536 bf16 = 128 KB
  float* out = (float*)d_out;

  pack_w2_kernel<<<256, 256, 0, stream>>>(W2, ws);
  odenet_kernel<<<256, 512, 0, stream>>>(x, W1, b1, ws, b2, W3, b3, s0, out);
}

// Round 15
// 1301.104 us; speedup vs baseline: 1.0758x; 1.0758x over previous
//
#include <hip/hip_runtime.h>

// ODENet: y_{t+1} = y_t + f(x_t, y_t),  f = W3^T tanh(W2^T tanh(x*W1[0] + y*W1[1] + b1) + b2) + b3
// out[t][b] = y_t (pre-update state).  SEQ=2048 sequential steps, BATCH=512 independent chains.
//
// Round-15: R14's single-barrier T/E-split MFMA with the two perf bugs fixed:
//  - E rows moved to MFMA rows m=1,5 (was 8,12): C-layout row=(lane>>4)*4+reg puts
//    accT in reg0 and accE in reg1 of the SAME lanes -> tail needs NO cross-lane shuffle:
//    h2pre = fma(s_lane, acc[1], acc[0]).
//  - LDA=288 for the 4 A-rows: row base bank = 16g mod 32 -> only (g,g+2) alias = 2-way
//    (free, m136). R14's LDA=264 gave 4-way (bank = 4(g+kg), sum-collisions, 1.34e8 cnt).
// Single barrier/step: A-write(T,E) -> BAR -> A-read + 16 MFMA; fold/y-update/next-T/E all
// in the MFMA shadow (T,E independent of fold -> linearized h1 = T + s*E applied POST-MFMA
// in fp32). A_lds and partial double-buffered; every cross-iter hazard spans a barrier.
// Retained: x preloaded to LDS, y staged to LDS + one flush, exp2-tanh (exact), DPP row16.

#define SEQ 2048
#define BATCH 512
#define HID 256
#define LDA 288  // 4-row padded stride: rows start at banks 0,16,0,16 -> worst 2-way (free)

typedef __bf16 bf16x8 __attribute__((ext_vector_type(8)));
typedef short short8 __attribute__((ext_vector_type(8)));
typedef float f32x4 __attribute__((ext_vector_type(4)));

__device__ __forceinline__ unsigned short f2bf_rne(float f) {
  unsigned u = __builtin_bit_cast(unsigned, f);
  u += 0x7fffu + ((u >> 16) & 1u);
  return (unsigned short)(u >> 16);
}

// Exact tanh via exp2: tanh(x) = 1 - 2/(exp2(2*log2e*x) + 1). No clamp needed.
__device__ __forceinline__ float tanh_e(float x) {
  float t = __builtin_amdgcn_exp2f(x * 2.8853900817779268f);
  return __builtin_fmaf(-2.f, __builtin_amdgcn_rcpf(t + 1.f), 1.f);
}

// Sum over each 16-lane DPP row; valid in lane 15 of the row.
__device__ __forceinline__ float row16_sum_to_lane15(float v) {
  int s;
  s = __builtin_amdgcn_update_dpp(0, __builtin_bit_cast(int, v), 0x111, 0xf, 0xf, true);
  v += __builtin_bit_cast(float, s);
  s = __builtin_amdgcn_update_dpp(0, __builtin_bit_cast(int, v), 0x112, 0xf, 0xf, true);
  v += __builtin_bit_cast(float, s);
  s = __builtin_amdgcn_update_dpp(0, __builtin_bit_cast(int, v), 0x114, 0xf, 0xf, true);
  v += __builtin_bit_cast(float, s);
  s = __builtin_amdgcn_update_dpp(0, __builtin_bit_cast(int, v), 0x118, 0xf, 0xf, true);
  v += __builtin_bit_cast(float, s);
  return v;
}

// Pack W2 (256x256 fp32, row-major [k][c]) into bf16 B-fragments.
// ws[(((tile*8)+kc)*64 + lane)*8 + e] = bf16(W2[k][c]) with
//   k = kc*32 + (lane>>4)*8 + e,  c = tile*16 + (lane&15)
__global__ void pack_w2_kernel(const float* __restrict__ W2,
                               unsigned short* __restrict__ ws) {
  int idx = blockIdx.x * 256 + threadIdx.x;     // 0..65535
  int e    = idx & 7;
  int l    = (idx >> 3) & 63;
  int kc   = (idx >> 9) & 7;
  int tile = idx >> 12;                         // 0..15
  int k = kc * 32 + (l >> 4) * 8 + e;
  int c = tile * 16 + (l & 15);
  ws[idx] = f2bf_rne(W2[k * HID + c]);
}

__global__ __launch_bounds__(512, 1) void odenet_kernel(
    const float* __restrict__ x, const float* __restrict__ W1,
    const float* __restrict__ b1, const unsigned short* __restrict__ wsW2,
    const float* __restrict__ b2, const float* __restrict__ W3,
    const float* __restrict__ b3, const float* __restrict__ state0,
    float* __restrict__ out) {
  __shared__ __align__(16) unsigned short A_lds[2][4 * LDA]; // [buf][rows T0,E0,T1,E1]
  __shared__ __align__(16) float partial[2][2][8];           // [buf][chain][wave]
  __shared__ __align__(16) float2 x_lds[SEQ];                // 16 KB
  __shared__ __align__(16) float2 y_lds[SEQ];                // 16 KB

  const int tid  = threadIdx.x;   // 0..511
  const int lane = tid & 63;
  const int wave = tid >> 6;      // 0..7
  const int rh   = tid >> 8;      // own chain
  const int j    = tid & 255;     // own h1 column
  const int b0   = blockIdx.x * 2;

  // --- persistent constants ---
  const float w10 = W1[j];
  const float w11 = W1[HID + j];
  const float b1j = b1[j];
  const float b3v = b3[0];
  const int c0 = wave * 32 + (lane & 15);
  const int c1 = c0 + 16;
  const float b2c0 = b2[c0], w3c0 = W3[c0];
  const float b2c1 = b2[c1], w3c1 = W3[c1];

  // --- B fragments: wave owns tiles {2w, 2w+1} ---
  short8 bf0[8], bf1[8];
  {
    const short8* wp = (const short8*)wsW2;
    const int t0 = wave * 2;
#pragma unroll
    for (int kc = 0; kc < 8; ++kc) {
      bf0[kc] = wp[((t0    ) * 8 + kc) * 64 + lane];
      bf1[kc] = wp[((t0 + 1) * 8 + kc) * 64 + lane];
    }
  }

  // --- preload x into LDS (one-time) ---
  {
    const float* xg = x + b0;
#pragma unroll
    for (int k = 0; k < 4; ++k) {
      const int t = tid + k * 512;
      x_lds[t] = *(const float2*)&xg[t * BATCH];
    }
  }

  // --- A-read addressing ---
  // MFMA A row m = lane&15; rows used: 0 (T0), 1 (E0), 4 (T1), 5 (E1).
  // Storage row g for this lane: g = ((lane>>1)&2) | (lane&1):
  //   lane&15==0 -> 0 (T0), ==1 -> 1 (E0), ==4 -> 2 (T1), ==5 -> 3 (E1); pad lanes dup.
  // Banks: addr bytes = g*576 + (lane>>4)*16 + kc*64 -> bank base 16g+4kg mod 32: only
  // (g,g+2) alias -> 2-way, free.
  const int g    = ((lane >> 1) & 2) | (lane & 1);
  const int aoff = g * LDA + (lane >> 4) * 8; // ushort index

  const f32x4 kZero = {0.f, 0.f, 0.f, 0.f};

  const float2 y_init = *(const float2*)&state0[b0];
  float y_own = rh ? y_init.y : y_init.x;

  // --- partials[1] init: fold at t=0 reads buf 1; 8 entries of -b3/8 -> s = -b3, f = 0 ---
  if (tid < 16) partial[1][tid >> 3][tid & 7] = -0.125f * b3v;

  // --- T/E for step 0 (x from global; x_lds not yet synced) ---
  float T, E;
  {
    const float2 x0 = *(const float2*)&x[b0];
    const float xv = rh ? x0.y : x0.x;
    const float xa0 = __builtin_fmaf(xv, w10, b1j);
    T = tanh_e(__builtin_fmaf(b3v, w11, __builtin_fmaf(y_own, w11, xa0)));
    E = w11 * __builtin_fmaf(-T, T, 1.f);
  }
  __syncthreads(); // x_lds + partial[1] visible (barrier preceding step 0)

  for (int t = 0; t < SEQ; ++t) {
    const int buf = t & 1;
    // --- write T,E rows (bf16): T -> storage 2*rh, E -> storage 2*rh+1 ---
    A_lds[buf][(2 * rh)     * LDA + j] = f2bf_rne(T);
    A_lds[buf][(2 * rh + 1) * LDA + j] = f2bf_rne(E);
    __syncthreads(); // THE barrier: T/E rows visible; prev partials visible

    // --- A-fragments ---
    const unsigned short* ab = &A_lds[buf][0];
    short8 areg[8];
#pragma unroll
    for (int kc = 0; kc < 8; ++kc)
      areg[kc] = *(const short8*)&ab[aoff + kc * 32];

    // --- 2 tiles x K=256: accT = acc[0], accE = acc[1] (rows 4rh, 4rh+1) ---
    f32x4 acc0, acc1;
    {
      const bf16x8 a = __builtin_bit_cast(bf16x8, areg[0]);
      acc0 = __builtin_amdgcn_mfma_f32_16x16x32_bf16(a, __builtin_bit_cast(bf16x8, bf0[0]), kZero, 0, 0, 0);
      acc1 = __builtin_amdgcn_mfma_f32_16x16x32_bf16(a, __builtin_bit_cast(bf16x8, bf1[0]), kZero, 0, 0, 0);
    }
#pragma unroll
    for (int kc = 1; kc < 8; ++kc) {
      const bf16x8 a = __builtin_bit_cast(bf16x8, areg[kc]);
      acc0 = __builtin_amdgcn_mfma_f32_16x16x32_bf16(a, __builtin_bit_cast(bf16x8, bf0[kc]), acc0, 0, 0, 0);
      acc1 = __builtin_amdgcn_mfma_f32_16x16x32_bf16(a, __builtin_bit_cast(bf16x8, bf1[kc]), acc1, 0, 0, 0);
    }

    // --- fold prev step's partials (MFMA shadow; independent of acc) ---
    const f32x4 q0a = *(const f32x4*)&partial[buf ^ 1][0][0];
    const f32x4 q0b = *(const f32x4*)&partial[buf ^ 1][0][4];
    const f32x4 q1a = *(const f32x4*)&partial[buf ^ 1][1][0];
    const f32x4 q1b = *(const f32x4*)&partial[buf ^ 1][1][4];
    const float s0sum = ((q0a[0] + q0a[1]) + (q0a[2] + q0a[3])) +
                        ((q0b[0] + q0b[1]) + (q0b[2] + q0b[3])); // = f(t-1) - b3
    const float s1sum = ((q1a[0] + q1a[1]) + (q1a[2] + q1a[3])) +
                        ((q1b[0] + q1b[1]) + (q1b[2] + q1b[3]));

    // --- y update -> Y_t, stage, next T/E (all in the MFMA shadow) ---
    const float s_own = rh ? s1sum : s0sum;
    y_own += s_own + b3v; // DT = 1.0; y_own = state entering step t
    if (j == 0) ((float*)&y_lds[t])[rh] = y_own;
    {
      const float2 xr = x_lds[(t + 1 < SEQ) ? t + 1 : t];
      const float xv = rh ? xr.y : xr.x;
      const float xaN = __builtin_fmaf(xv, w10, b1j);
      T = tanh_e(__builtin_fmaf(b3v, w11, __builtin_fmaf(y_own, w11, xaN)));
      E = w11 * __builtin_fmaf(-T, T, 1.f);
    }

    // --- tail: h2pre = accT + s*accE (both in-lane), tanh, dot W3, reduce ---
    const float s_lane = ((lane >> 4) & 1) ? s1sum : s0sum; // chain of this 16-group
    const float h0 = __builtin_fmaf(s_lane, acc0[1], acc0[0]);
    const float h1v = __builtin_fmaf(s_lane, acc1[1], acc1[0]);
    const float sres = tanh_e(h0 + b2c0) * w3c0 +
                       tanh_e(h1v + b2c1) * w3c1;
    const float r = row16_sum_to_lane15(sres);
    if ((lane & 15) == 15 && lane < 32)
      partial[buf][lane >> 4][wave] = r; // read at t+1 after its barrier
    // no second barrier: all cross-iteration hazards span the next iteration's barrier
  }

  __syncthreads(); // y_lds writes visible to all threads for the flush
#pragma unroll
  for (int k = 0; k < 4; ++k) {
    const int t = tid + k * 512;
    *(float2*)&out[t * BATCH + b0] = y_lds[t];
  }
}

extern "C" void kernel_launch(void* const* d_in, const int* in_sizes, int n_in,
                              void* d_out, int out_size, void* d_ws, size_t ws_size,
                              hipStream_t stream) {
  const float* x  = (const float*)d_in[0];
  const float* W1 = (const float*)d_in[1];
  const float* b1 = (const float*)d_in[2];
  const float* W2 = (const float*)d_in[3];
  const float* b2 = (const float*)d_in[4];
  const float* W3 = (const float*)d_in[5];
  const float* b3 = (const float*)d_in[6];
  const float* s0 = (const float*)d_in[7];
  unsigned short* ws = (unsigned short*)d_ws; // 65536 bf16 = 128 KB
  float* out = (float*)d_out;

  pack_w2_kernel<<<256, 256, 0, stream>>>(W2, ws);
  odenet_kernel<<<256, 512, 0, stream>>>(x, W1, b1, ws, b2, W3, b3, s0, out);
}